// Round 11
// baseline (156.466 us; speedup 1.0000x reference)
//
#include <hip/hip_runtime.h>
#include <float.h>

// Problem constants (B=8, N=8192, D=3)
#define NB 8
#define NPTS 8192
#define TOTAL (NB * NPTS)             // 65536
#define BLK 256
#define WAVES 4
#define GROUPS 8                      // 32-col MFMA groups per wave
#define ADV_PER_WAVE (GROUPS * 32)    // 256
#define ADV_PER_BLOCK (WAVES * ADV_PER_WAVE)   // 1024
#define ADV_BLOCKS (TOTAL / ADV_PER_BLOCK)     // 64 (8 per batch)
#define OSPLIT 16                     // ori split -> partial mins
#define OSLICE (NPTS / OSPLIT)        // 512 ori records per block (16 KB LDS)
#define REC_SHORTS 16                 // 32 B per ori record
#define NTILES (OSLICE / 32)          // 16 MFMA tiles per block
#define GRID_MAIN (ADV_BLOCKS * OSPLIT)        // 1024 blocks
#define BF16_ONE 0x3F80

typedef short short8 __attribute__((ext_vector_type(8)));
typedef float floatx16 __attribute__((ext_vector_type(16)));

__device__ __forceinline__ unsigned short f2bf(float f) {   // RNE, no NaNs here
    unsigned int u = __float_as_uint(f);
    return (unsigned short)((u + 0x7FFFu + ((u >> 16) & 1u)) >> 16);
}
__device__ __forceinline__ float bf2f(unsigned short h) {
    return __uint_as_float(((unsigned int)h) << 16);
}
__device__ __forceinline__ float min3(float a, float b, float c) {
    return fminf(fminf(a, b), c);                 // -> v_min3_f32
}
// 16 accum values + carry-in um in 8 v_min3
__device__ __forceinline__ float fold16(floatx16 d, float um) {
    float t0 = min3(d[0], d[1], d[2]);
    float t1 = min3(d[3], d[4], d[5]);
    float t2 = min3(d[6], d[7], d[8]);
    float t3 = min3(d[9], d[10], d[11]);
    float t4 = min3(d[12], d[13], d[14]);
    float t5 = min3(t0, t1, d[15]);
    float t6 = min3(t2, t3, t4);
    return min3(t5, t6, um);
}

// ---- main: 32x32x16 bf16 MFMA brute force, hand-software-pipelined ----
// K-slot map (11 of 16 used):
//  k0..2: oh*(-2ah)  k3..5: ol*(-2ah)  k6..8: oh*(-2al)  k9: roh*1  k10: rol*1
// A record (ori): [ohx,ohy,ohz, olx,oly,olz, ohx,ohy | ohz, roh, rol, 0 x5]
// B half0: [-2ahx,-2ahy,-2ahz, -2ahx,-2ahy,-2ahz, -2alx,-2aly]; half1: [-2alz,1,1,0..]
// D[m][n] = ro_m - 2 dot(o_m, a_n)  (hi/lo split, exact in fp32 accum);
// d_n = ra_n + min_m D[m][n]  (ra exact fp32).
// Pipelining: d[8] holds tile t-1's results; steady loop issues MFMA(t,g)
// then fold(t-1,g) -> every fold's operand is 8 MFMAs (~258 matrix-cyc) old,
// so MFMA result latency is never exposed and the matrix pipe streams.
// d[] starts at FLT_MAX so the loop is uniform (dummy fold is a min no-op).
__global__ __launch_bounds__(BLK, 2) void chamfer_mfma(const float* __restrict__ adv,
                                                       const float* __restrict__ ori,
                                                       float* __restrict__ partial,
                                                       float* __restrict__ out) {
    __shared__ __align__(16) unsigned short lrec[OSLICE * REC_SHORTS];   // 16 KB
    __shared__ __align__(16) float advS[ADV_PER_BLOCK * 3];              // 12 KB
    const int tid = threadIdx.x;
    const int wave = tid >> 6, lane = tid & 63;
    const int n32 = lane & 31, half = lane >> 5;
    const int advBlk = blockIdx.x >> 4;            // 0..63
    const int split = blockIdx.x & 15;
    const int b = advBlk >> 3;                     // 8 adv-blocks per batch
    const int advLocal = (advBlk & 7) * ADV_PER_BLOCK;

    if (blockIdx.x == 0 && tid == 0) out[0] = 0.0f;   // replaces memset node

    if (tid < 128) {
        // ---- build 4 ori records from 3 float4 loads ----
        const float4* op = (const float4*)(ori + (size_t)(b * NPTS + split * OSLICE) * 3);
        float4 f0 = op[tid * 3 + 0], f1 = op[tid * 3 + 1], f2 = op[tid * 3 + 2];
        float px[4] = {f0.x, f0.w, f1.z, f2.y};
        float py[4] = {f0.y, f1.x, f1.w, f2.z};
        float pz[4] = {f0.z, f1.y, f2.x, f2.w};
#pragma unroll
        for (int r = 0; r < 4; r++) {
            float x = px[r], y = py[r], z = pz[r];
            unsigned short hx = f2bf(x), hy = f2bf(y), hz = f2bf(z);
            unsigned short lx = f2bf(x - bf2f(hx));
            unsigned short ly = f2bf(y - bf2f(hy));
            unsigned short lz = f2bf(z - bf2f(hz));
            float ro = fmaf(x, x, fmaf(y, y, z * z));
            unsigned short rh = f2bf(ro), rl = f2bf(ro - bf2f(rh));
            __align__(16) unsigned short rec[16] = {hx, hy, hz, lx, ly, lz, hx, hy,
                                                    hz, rh, rl, 0, 0, 0, 0, 0};
            float4* dst = (float4*)&lrec[(tid * 4 + r) * REC_SHORTS];
            dst[0] = ((float4*)rec)[0];
            dst[1] = ((float4*)rec)[1];
        }
    } else {
        // ---- stage 1024 adv points (768 float4) into LDS, coalesced ----
        const int tt = tid - 128;
        const float4* gadv4 = (const float4*)(adv + (size_t)b * NPTS * 3 + (size_t)advLocal * 3);
        float4* s4 = (float4*)advS;
#pragma unroll
        for (int i = 0; i < 6; i++) s4[tt + i * 128] = gadv4[tt + i * 128];
    }
    __syncthreads();

    // ---- B-fragments from LDS (lanes l and l+32 read same addr: broadcast) ----
    short8 bfr[GROUPS];
    float ra[GROUPS], um[GROUPS];
#pragma unroll
    for (int g = 0; g < GROUPS; g++) {
        int j = (wave * ADV_PER_WAVE + g * 32 + n32) * 3;
        float x = advS[j + 0], y = advS[j + 1], z = advS[j + 2];
        ra[g] = fmaf(x, x, fmaf(y, y, z * z));
        um[g] = FLT_MAX;
        unsigned short hx = f2bf(x), hy = f2bf(y), hz = f2bf(z);
        float fhx = bf2f(hx), fhy = bf2f(hy), fhz = bf2f(hz);
        unsigned short nhx = f2bf(-2.0f * fhx), nhy = f2bf(-2.0f * fhy), nhz = f2bf(-2.0f * fhz);
        unsigned short nlx = f2bf(-2.0f * bf2f(f2bf(x - fhx)));
        unsigned short nly = f2bf(-2.0f * bf2f(f2bf(y - fhy)));
        unsigned short nlz = f2bf(-2.0f * bf2f(f2bf(z - fhz)));
        __align__(16) unsigned short e[8] = {0, 0, 0, 0, 0, 0, 0, 0};
        if (half == 0) {
            e[0] = nhx; e[1] = nhy; e[2] = nhz;
            e[3] = nhx; e[4] = nhy; e[5] = nhz;
            e[6] = nlx; e[7] = nly;
        } else {
            e[0] = nlz; e[1] = BF16_ONE; e[2] = BF16_ONE;
        }
        bfr[g] = *(short8*)e;
    }

    const floatx16 zero = {0.f, 0.f, 0.f, 0.f, 0.f, 0.f, 0.f, 0.f,
                           0.f, 0.f, 0.f, 0.f, 0.f, 0.f, 0.f, 0.f};
    const int lsh = n32 * REC_SHORTS + half * 8;   // per-lane A-frag offset in a tile

    // ---- pipelined main loop ----
    floatx16 d[GROUPS];
#pragma unroll
    for (int g = 0; g < GROUPS; g++)
#pragma unroll
        for (int i = 0; i < 16; i++) d[g][i] = FLT_MAX;

    short8 af = *(const short8*)&lrec[lsh];        // tile 0
#pragma unroll 1
    for (int t = 0; t < NTILES; t++) {
        short8 afn = *(const short8*)&lrec[(((t + 1) & (NTILES - 1)) * 32 * REC_SHORTS) + lsh];
#pragma unroll
        for (int g = 0; g < GROUPS; g++) {
            floatx16 dn = __builtin_amdgcn_mfma_f32_32x32x16_bf16(af, bfr[g], zero, 0, 0, 0);
            um[g] = fold16(d[g], um[g]);           // folds tile t-1 (8 MFMAs old)
            d[g] = dn;
        }
        af = afn;
    }
#pragma unroll
    for (int g = 0; g < GROUPS; g++) um[g] = fold16(d[g], um[g]);   // last tile

    // rows per lane: half=0 -> {0-3,8-11,16-19,24-27}; shfl 32 folds the rest
#pragma unroll
    for (int g = 0; g < GROUPS; g++) {
        float v = fminf(um[g], __shfl_xor(um[g], 32, 64));
        if (half == 0) {
            int col = b * NPTS + advLocal + wave * ADV_PER_WAVE + g * 32 + n32;
            partial[(size_t)split * TOTAL + col] = ra[g] + v;
        }
    }
}

// ---- reduce: min over 16 splits + weighted mean; 256 blocks x 64 threads ----
__global__ __launch_bounds__(64) void reduce_mins(const float* __restrict__ partial,
                                                  const float* __restrict__ w,
                                                  float* __restrict__ out) {
    const float4* p4 = (const float4*)partial;
    int g4 = blockIdx.x * 64 + threadIdx.x;        // 16384 float4 groups
    float4 m = p4[g4];
#pragma unroll
    for (int s = 1; s < OSPLIT; s++) {
        float4 v = p4[(size_t)s * (TOTAL / 4) + g4];
        m.x = fminf(m.x, v.x); m.y = fminf(m.y, v.y);
        m.z = fminf(m.z, v.z); m.w = fminf(m.w, v.w);
    }
    // 4 consecutive points share a batch (batch stride 8192 pts = 2048 float4)
    float v = ((m.x + m.y) + (m.z + m.w)) * w[g4 >> 11];
#pragma unroll
    for (int s = 32; s > 0; s >>= 1) v += __shfl_down(v, s, 64);
    if (threadIdx.x == 0) atomicAdd(out, v * (1.0f / (float)TOTAL));
}

extern "C" void kernel_launch(void* const* d_in, const int* in_sizes, int n_in,
                              void* d_out, int out_size, void* d_ws, size_t ws_size,
                              hipStream_t stream) {
    const float* adv = (const float*)d_in[0];   // [8,8192,3] f32
    const float* ori = (const float*)d_in[1];   // [8,8192,3] f32
    const float* w   = (const float*)d_in[2];   // [8] f32
    float* out = (float*)d_out;
    float* partial = (float*)d_ws;              // 16 * 64K floats = 4 MB

    hipLaunchKernelGGL(chamfer_mfma, dim3(GRID_MAIN), dim3(BLK), 0, stream,
                       adv, ori, partial, out);
    hipLaunchKernelGGL(reduce_mins, dim3(TOTAL / 4 / 64), dim3(64), 0, stream,
                       partial, w, out);
}

// Round 12
// 79.111 us; speedup vs baseline: 1.9778x; 1.9778x over previous
//
#include <hip/hip_runtime.h>
#include <float.h>

// Problem constants (B=8, N=8192, D=3)
#define NB 8
#define NPTS 8192
#define TOTAL (NB * NPTS)             // 65536
#define BLK 256
#define WAVES 4
#define GROUPS 4                      // 32-col MFMA groups per wave (reg-sized!)
#define ADV_PER_WAVE (GROUPS * 32)    // 128
#define ADV_PER_BLOCK (WAVES * ADV_PER_WAVE)   // 512
#define ADV_BLOCKS (TOTAL / ADV_PER_BLOCK)     // 128 (16 per batch)
#define OSPLIT 8                      // ori split -> partial mins
#define OSLICE (NPTS / OSPLIT)        // 1024 ori records per block (32 KB LDS)
#define REC_SHORTS 16                 // 32 B per ori record
#define NTILES (OSLICE / 32)          // 32 MFMA tiles per block
#define GRID_MAIN (ADV_BLOCKS * OSPLIT)        // 1024 blocks -> 4 blocks/CU
#define BF16_ONE 0x3F80

typedef short short8 __attribute__((ext_vector_type(8)));
typedef float floatx16 __attribute__((ext_vector_type(16)));

__device__ __forceinline__ unsigned short f2bf(float f) {   // RNE, no NaNs here
    unsigned int u = __float_as_uint(f);
    return (unsigned short)((u + 0x7FFFu + ((u >> 16) & 1u)) >> 16);
}
__device__ __forceinline__ float bf2f(unsigned short h) {
    return __uint_as_float(((unsigned int)h) << 16);
}
__device__ __forceinline__ float min3(float a, float b, float c) {
    return fminf(fminf(a, b), c);                 // -> v_min3_f32
}
// 16 accum values + carry-in um in 8 v_min3
__device__ __forceinline__ float fold16(floatx16 d, float um) {
    float t0 = min3(d[0], d[1], d[2]);
    float t1 = min3(d[3], d[4], d[5]);
    float t2 = min3(d[6], d[7], d[8]);
    float t3 = min3(d[9], d[10], d[11]);
    float t4 = min3(d[12], d[13], d[14]);
    float t5 = min3(t0, t1, d[15]);
    float t6 = min3(t2, t3, t4);
    return min3(t5, t6, um);
}

// ---- main: 32x32x16 bf16 MFMA brute force, depth-2 software pipeline ----
// K-slot map (11 of 16 used):
//  k0..2: oh*(-2ah)  k3..5: ol*(-2ah)  k6..8: oh*(-2al)  k9: roh*1  k10: rol*1
// A record (ori): [ohx,ohy,ohz, olx,oly,olz, ohx,ohy | ohz, roh, rol, 0 x5]
// B half0: [-2ahx,-2ahy,-2ahz, -2ahx,-2ahy,-2ahz, -2alx,-2aly]; half1: [-2alz,1,1,0..]
// D[m][n] = ro_m - 2 dot(o_m, a_n)  (hi/lo split, exact in fp32 accum);
// d_n = ra_n + min_m D[m][n]  (ra exact fp32).
// Pipeline: dbuf[4] (64 VGPR), step i folds step i-2 -> MFMA latency covered
// by 2 MFMA issues + one fold; GROUPS=4 keeps total VGPR ~116 (no spill,
// the R11 lesson: d[8] = 128 VGPRs spilled to scratch, 144 MB of traffic).
__global__ __launch_bounds__(BLK, 4) void chamfer_mfma(const float* __restrict__ adv,
                                                       const float* __restrict__ ori,
                                                       float* __restrict__ partial,
                                                       float* __restrict__ out) {
    __shared__ __align__(16) unsigned short lrec[OSLICE * REC_SHORTS];   // 32 KB
    __shared__ __align__(16) float advS[ADV_PER_BLOCK * 3];              // 6 KB
    const int tid = threadIdx.x;
    const int wave = tid >> 6, lane = tid & 63;
    const int n32 = lane & 31, half = lane >> 5;
    const int advBlk = blockIdx.x >> 3;            // 0..127
    const int split = blockIdx.x & 7;
    const int b = advBlk >> 4;                     // 16 adv-blocks per batch
    const int advLocal = (advBlk & 15) * ADV_PER_BLOCK;

    if (blockIdx.x == 0 && tid == 0) out[0] = 0.0f;   // replaces memset node

    if (tid < 128) {
        // ---- build 8 ori records from 6 float4 loads ----
        const float4* op = (const float4*)(ori + (size_t)(b * NPTS + split * OSLICE) * 3);
        float4 f0 = op[tid * 6 + 0], f1 = op[tid * 6 + 1], f2 = op[tid * 6 + 2];
        float4 f3 = op[tid * 6 + 3], f4 = op[tid * 6 + 4], f5 = op[tid * 6 + 5];
        float px[8] = {f0.x, f0.w, f1.z, f2.y, f3.x, f3.w, f4.z, f5.y};
        float py[8] = {f0.y, f1.x, f1.w, f2.z, f3.y, f4.x, f4.w, f5.z};
        float pz[8] = {f0.z, f1.y, f2.x, f2.w, f3.z, f4.y, f5.x, f5.w};
#pragma unroll
        for (int r = 0; r < 8; r++) {
            float x = px[r], y = py[r], z = pz[r];
            unsigned short hx = f2bf(x), hy = f2bf(y), hz = f2bf(z);
            unsigned short lx = f2bf(x - bf2f(hx));
            unsigned short ly = f2bf(y - bf2f(hy));
            unsigned short lz = f2bf(z - bf2f(hz));
            float ro = fmaf(x, x, fmaf(y, y, z * z));
            unsigned short rh = f2bf(ro), rl = f2bf(ro - bf2f(rh));
            __align__(16) unsigned short rec[16] = {hx, hy, hz, lx, ly, lz, hx, hy,
                                                    hz, rh, rl, 0, 0, 0, 0, 0};
            float4* dst = (float4*)&lrec[(tid * 8 + r) * REC_SHORTS];
            dst[0] = ((float4*)rec)[0];
            dst[1] = ((float4*)rec)[1];
        }
    } else {
        // ---- stage 512 adv points (384 float4) into LDS, coalesced ----
        const int tt = tid - 128;
        const float4* gadv4 = (const float4*)(adv + (size_t)b * NPTS * 3 + (size_t)advLocal * 3);
        float4* s4 = (float4*)advS;
#pragma unroll
        for (int i = 0; i < 3; i++) s4[tt + i * 128] = gadv4[tt + i * 128];
    }
    __syncthreads();

    // ---- B-fragments from LDS (lanes l and l+32 read same addr: broadcast) ----
    short8 bfr[GROUPS];
    float ra[GROUPS], um[GROUPS];
#pragma unroll
    for (int g = 0; g < GROUPS; g++) {
        int j = (wave * ADV_PER_WAVE + g * 32 + n32) * 3;
        float x = advS[j + 0], y = advS[j + 1], z = advS[j + 2];
        ra[g] = fmaf(x, x, fmaf(y, y, z * z));
        um[g] = FLT_MAX;
        unsigned short hx = f2bf(x), hy = f2bf(y), hz = f2bf(z);
        float fhx = bf2f(hx), fhy = bf2f(hy), fhz = bf2f(hz);
        unsigned short nhx = f2bf(-2.0f * fhx), nhy = f2bf(-2.0f * fhy), nhz = f2bf(-2.0f * fhz);
        unsigned short nlx = f2bf(-2.0f * bf2f(f2bf(x - fhx)));
        unsigned short nly = f2bf(-2.0f * bf2f(f2bf(y - fhy)));
        unsigned short nlz = f2bf(-2.0f * bf2f(f2bf(z - fhz)));
        __align__(16) unsigned short e[8] = {0, 0, 0, 0, 0, 0, 0, 0};
        if (half == 0) {
            e[0] = nhx; e[1] = nhy; e[2] = nhz;
            e[3] = nhx; e[4] = nhy; e[5] = nhz;
            e[6] = nlx; e[7] = nly;
        } else {
            e[0] = nlz; e[1] = BF16_ONE; e[2] = BF16_ONE;
        }
        bfr[g] = *(short8*)e;
    }

    const floatx16 zero = {0.f, 0.f, 0.f, 0.f, 0.f, 0.f, 0.f, 0.f,
                           0.f, 0.f, 0.f, 0.f, 0.f, 0.f, 0.f, 0.f};
    const int lsh = n32 * REC_SHORTS + half * 8;   // per-lane A-frag offset in a tile

    // ---- depth-2 pipelined main loop ----
    // step i = t*4+g: issue MFMA(i) -> dbuf[g]; fold step i-2 (buffer (g+2)&3
    // into um[(g+2)&3]). 4 steps/tile == 0 mod 4 -> indices static per unroll.
    floatx16 dbuf[4];
#pragma unroll
    for (int q = 0; q < 4; q++)
#pragma unroll
        for (int i = 0; i < 16; i++) dbuf[q][i] = FLT_MAX;   // dummy: min no-op

    short8 af = *(const short8*)&lrec[lsh];        // tile 0
#pragma unroll 1
    for (int t = 0; t < NTILES; t++) {
        short8 afn = *(const short8*)&lrec[(((t + 1) & (NTILES - 1)) * 32 * REC_SHORTS) + lsh];
#pragma unroll
        for (int g = 0; g < GROUPS; g++) {
            floatx16 dn = __builtin_amdgcn_mfma_f32_32x32x16_bf16(af, bfr[g], zero, 0, 0, 0);
            um[(g + 2) & 3] = fold16(dbuf[(g + 2) & 3], um[(g + 2) & 3]);
            dbuf[g] = dn;
        }
        af = afn;
    }
    // drain: steps 4*NTILES-2 (g=2) and -1 (g=3) were never folded in-loop
    um[2] = fold16(dbuf[2], um[2]);
    um[3] = fold16(dbuf[3], um[3]);

    // rows per lane: half=0 -> {0-3,8-11,16-19,24-27}; shfl 32 folds the rest
#pragma unroll
    for (int g = 0; g < GROUPS; g++) {
        float v = fminf(um[g], __shfl_xor(um[g], 32, 64));
        if (half == 0) {
            int col = b * NPTS + advLocal + wave * ADV_PER_WAVE + g * 32 + n32;
            partial[(size_t)split * TOTAL + col] = ra[g] + v;
        }
    }
}

// ---- reduce: min over 8 splits + weighted mean; 256 blocks x 64 threads ----
__global__ __launch_bounds__(64) void reduce_mins(const float* __restrict__ partial,
                                                  const float* __restrict__ w,
                                                  float* __restrict__ out) {
    const float4* p4 = (const float4*)partial;
    int g4 = blockIdx.x * 64 + threadIdx.x;        // 16384 float4 groups
    float4 m = p4[g4];
#pragma unroll
    for (int s = 1; s < OSPLIT; s++) {
        float4 v = p4[(size_t)s * (TOTAL / 4) + g4];
        m.x = fminf(m.x, v.x); m.y = fminf(m.y, v.y);
        m.z = fminf(m.z, v.z); m.w = fminf(m.w, v.w);
    }
    // 4 consecutive points share a batch (batch stride 8192 pts = 2048 float4)
    float v = ((m.x + m.y) + (m.z + m.w)) * w[g4 >> 11];
#pragma unroll
    for (int s = 32; s > 0; s >>= 1) v += __shfl_down(v, s, 64);
    if (threadIdx.x == 0) atomicAdd(out, v * (1.0f / (float)TOTAL));
}

extern "C" void kernel_launch(void* const* d_in, const int* in_sizes, int n_in,
                              void* d_out, int out_size, void* d_ws, size_t ws_size,
                              hipStream_t stream) {
    const float* adv = (const float*)d_in[0];   // [8,8192,3] f32
    const float* ori = (const float*)d_in[1];   // [8,8192,3] f32
    const float* w   = (const float*)d_in[2];   // [8] f32
    float* out = (float*)d_out;
    float* partial = (float*)d_ws;              // 8 * 64K floats = 2 MB

    hipLaunchKernelGGL(chamfer_mfma, dim3(GRID_MAIN), dim3(BLK), 0, stream,
                       adv, ori, partial, out);
    hipLaunchKernelGGL(reduce_mins, dim3(TOTAL / 4 / 64), dim3(64), 0, stream,
                       partial, w, out);
}